// Round 1
// 211.603 us; speedup vs baseline: 1.0136x; 1.0136x over previous
//
#include <hip/hip_runtime.h>
#include <hip/hip_bf16.h>

// MoE: N=8192 tokens, D=1024, E=8 experts, top-2 routing.
// Inputs (fp32): x[8192,1024], Wr[1024,8], br[8], W[8,1024,1024], b[8,1024]
// Output (fp32): out[8192,1024]
//
// R1: block-aggregated scatter (router atomics 16384 -> 128).
// R2: dense tile list. R3: split-K regressed (epilogue-dominated).
// R4: atomic-free epilogue (slot-major bf16 ybuf + combine), eff. BK=64.
// R5: pipeline fusion 6 kernels -> 3:
//     prep_kernel = transpose(2048 blk) + router+scatter(128 blk, 64 tok/blk,
//     block-aggregated slot claims) + last-block tile build (done-counter).
//     combine: 4 tokens/block. GEMM untouched (control for this round).

#define NTOK 8192
#define DM   1024
#define NEXP 8
#define CAP  8192    // per-expert slot capacity (worst case)
#define MAXT 136     // max total m-tiles

#define TRB  2048    // transpose blocks in prep grid
#define RTB  128     // router blocks in prep grid (64 tokens each)

typedef __attribute__((ext_vector_type(8))) short bf16x8;
typedef __attribute__((ext_vector_type(4))) float f32x4;

__device__ __forceinline__ unsigned short f2bf(float f) {
  unsigned u = __float_as_uint(f);
  unsigned r = (u + 0x7fffu + ((u >> 16) & 1u)) >> 16;
  return (unsigned short)r;
}
__device__ __forceinline__ float bf2f(unsigned short s) {
  return __uint_as_float(((unsigned)s) << 16);
}

__device__ __forceinline__ void gl_lds16(const void* g, void* l) {
  __builtin_amdgcn_global_load_lds(
      (const __attribute__((address_space(1))) unsigned int*)g,
      (__attribute__((address_space(3))) unsigned int*)l, 16, 0, 0);
}

// ---------------- Fused prep: W transpose+cast | router+scatter+tilebuild ---
// Blocks [0, TRB): Wt[e][h][d] = bf16(W[e][d][h])  (64x64 fp32 LDS transpose)
// Blocks [TRB, TRB+RTB): 64 tokens each — router logits, top-2 gates, bf16
//   cast of x, block-aggregated slot scatter (8 global atomics/block).
//   Last router block (device done-counter) builds tile descs + offsets.
__global__ __launch_bounds__(256) void prep_kernel(
    const float* __restrict__ W, unsigned short* __restrict__ Wt,
    const float* __restrict__ x, const float* __restrict__ Wr,
    const float* __restrict__ br, unsigned short* __restrict__ xbf,
    int4* __restrict__ topk, int* __restrict__ counts,
    int* __restrict__ tok, int2* __restrict__ pos,
    int* __restrict__ done, int* __restrict__ desc,
    int* __restrict__ ntiles, int* __restrict__ offset) {
  __shared__ __align__(16) float smem[64 * 65];
  const int tid = threadIdx.x;

  if (blockIdx.x < TRB) {
    // ---- transpose branch ----
    float (*tile)[65] = (float(*)[65])smem;
    const int e = blockIdx.x >> 8;
    const int rem = blockIdx.x & 255;
    const int d0 = (rem >> 4) * 64, h0 = (rem & 15) * 64;
    const float* Ws = W + (size_t)e * DM * DM;
    unsigned short* Wd = Wt + (size_t)e * DM * DM;
    const int r = tid >> 4;           // 0..15
    const int c4 = (tid & 15) * 4;    // 0..60
#pragma unroll
    for (int k = 0; k < 4; k++) {
      int row = r + k * 16;
      float4 v = *(const float4*)(Ws + (size_t)(d0 + row) * DM + h0 + c4);
      tile[row][c4 + 0] = v.x; tile[row][c4 + 1] = v.y;
      tile[row][c4 + 2] = v.z; tile[row][c4 + 3] = v.w;
    }
    __syncthreads();
#pragma unroll
    for (int k = 0; k < 4; k++) {
      int hrow = r + k * 16;
      ushort4 o;
      o.x = f2bf(tile[c4 + 0][hrow]);
      o.y = f2bf(tile[c4 + 1][hrow]);
      o.z = f2bf(tile[c4 + 2][hrow]);
      o.w = f2bf(tile[c4 + 3][hrow]);
      *(ushort4*)(Wd + (size_t)(h0 + hrow) * DM + d0 + c4) = o;
    }
    return;
  }

  // ---- router + scatter branch ----
  int*  lcnt  = (int*)smem;                  // 8 ints  (counts, then bases)
  int4* ltop  = (int4*)(smem + 16);          // 64 int4 (e0,e1,g0,g1)
  int2* lrank = (int2*)(smem + 16 + 256);    // 64 int2 (block-local ranks)

  const int rb = blockIdx.x - TRB;
  const int wave = tid >> 6, lane = tid & 63;
  const int tbase = rb * 64;
  if (tid < NEXP) lcnt[tid] = 0;

  const int c0 = lane * 16;
  const float* wr = Wr + (size_t)c0 * NEXP;

#pragma unroll 1
  for (int it = 0; it < 16; it++) {
    const int t = tbase + wave * 16 + it;
    const float* xr = x + (size_t)t * DM + c0;
    float v[16];
#pragma unroll
    for (int i = 0; i < 4; i++) {
      float4 f = *(const float4*)(xr + i * 4);
      v[i * 4 + 0] = f.x; v[i * 4 + 1] = f.y;
      v[i * 4 + 2] = f.z; v[i * 4 + 3] = f.w;
    }
    union { unsigned short s[8]; uint4 q; } pk;
#pragma unroll
    for (int half = 0; half < 2; half++) {
#pragma unroll
      for (int i = 0; i < 8; i++) pk.s[i] = f2bf(v[half * 8 + i]);
      *(uint4*)(xbf + (size_t)t * DM + c0 + half * 8) = pk.q;
    }
    float p[8] = {0, 0, 0, 0, 0, 0, 0, 0};
#pragma unroll
    for (int i = 0; i < 16; i++) {
      float xv = v[i];
      float4 wl = *(const float4*)(wr + i * 8);
      float4 wh = *(const float4*)(wr + i * 8 + 4);
      p[0] += xv * wl.x; p[1] += xv * wl.y; p[2] += xv * wl.z; p[3] += xv * wl.w;
      p[4] += xv * wh.x; p[5] += xv * wh.y; p[6] += xv * wh.z; p[7] += xv * wh.w;
    }
#pragma unroll
    for (int off = 32; off >= 1; off >>= 1) {
#pragma unroll
      for (int e = 0; e < 8; e++) p[e] += __shfl_xor(p[e], off, 64);
    }
    if (lane == 0) {
      float lg[8];
#pragma unroll
      for (int e = 0; e < 8; e++) lg[e] = p[e] + br[e];
      float v0 = lg[0]; int i0 = 0;
#pragma unroll
      for (int e = 1; e < 8; e++) if (lg[e] > v0) { v0 = lg[e]; i0 = e; }
      float v1 = -3.4e38f; int i1 = 0;
#pragma unroll
      for (int e = 0; e < 8; e++)
        if (e != i0 && lg[e] > v1) { v1 = lg[e]; i1 = e; }
      float ee = __expf(v1 - v0);
      float g0 = 1.0f / (1.0f + ee);
      float g1 = ee / (1.0f + ee);
      int4 rec;
      rec.x = i0; rec.y = i1;
      rec.z = __float_as_int(g0); rec.w = __float_as_int(g1);
      ltop[wave * 16 + it] = rec;
      topk[t] = rec;
    }
  }
  __syncthreads();

  // block-local slot ranks
  if (tid < 64) {
    int4 r = ltop[tid];
    int s0 = atomicAdd(&lcnt[r.x], 1);
    int s1 = atomicAdd(&lcnt[r.y], 1);
    int2 rk; rk.x = s0; rk.y = s1;
    lrank[tid] = rk;
  }
  __syncthreads();
  // global bases (8 atomics/block); lcnt becomes base
  if (tid < NEXP) lcnt[tid] = atomicAdd(&counts[tid], lcnt[tid]);
  __syncthreads();
  if (tid < 64) {
    int4 r = ltop[tid];
    int2 rk = lrank[tid];
    int p0 = lcnt[r.x] + rk.x;
    int p1 = lcnt[r.y] + rk.y;
    int t = tbase + tid;
    tok[r.x * CAP + p0] = t;
    tok[r.y * CAP + p1] = t;
    int2 pr; pr.x = p0; pr.y = p1;
    pos[t] = pr;
  }
  __syncthreads();

  // last router block builds tile descriptors + expert offsets
  if (tid == 0) {
    __threadfence();
    if (atomicAdd(done, 1) == RTB - 1) {
      __threadfence();
      int cnt[NEXP];
#pragma unroll
      for (int e = 0; e < NEXP; e++) cnt[e] = atomicAdd(&counts[e], 0);
      int idx = 0, off = 0;
#pragma unroll
      for (int e = 0; e < NEXP; e++) {
        offset[e] = off;
        off += cnt[e];
        int nm = (cnt[e] + 127) >> 7;
        for (int i = 0; i < nm; i++) desc[idx++] = (e << 16) | i;
      }
      *ntiles = idx;
    }
  }
}

// ---------------- Routed expert GEMM -> slot-major bf16 ybuf ----------------
// Tile 128x128, two BK=32 stages per barrier (eff. BK=64), 4 waves 2x2.
// Epilogue: plain bf16 stores of raw acc (gates/bias applied in combine).
__global__ __launch_bounds__(256) void moe_gemm_kernel(
    const unsigned short* __restrict__ xbf, const unsigned short* __restrict__ wt,
    const int* __restrict__ counts, const int* __restrict__ offset,
    const int* __restrict__ tok, const int* __restrict__ desc,
    const int* __restrict__ ntiles, unsigned short* __restrict__ ybuf) {
  const int slot = blockIdx.y;
  if (slot >= *ntiles) return;
  const int dsc = desc[slot];
  const int e = dsc >> 16;
  const int m0 = (dsc & 0xffff) * 128;
  const int cnt = counts[e];
  const int n0 = blockIdx.x * 128;

  __shared__ __align__(16) unsigned short sA0[128 * 32];
  __shared__ __align__(16) unsigned short sB0[128 * 32];
  __shared__ __align__(16) unsigned short sA1[128 * 32];
  __shared__ __align__(16) unsigned short sB1[128 * 32];
  __shared__ int sTok[128];

  const int tid = threadIdx.x, wave = tid >> 6, lane = tid & 63;

  if (tid < 128) {
    int sr = m0 + tid;
    int cl = (sr < cnt) ? sr : (cnt - 1);
    sTok[tid] = tok[e * CAP + cl];
  }
  __syncthreads();

  // staging: wave w stages 16-row groups {w, w+4}; lane i -> row g*16+(i>>2),
  // chunk slot i&3; source chunk XOR-swizzled (2-way LDS aliasing = free).
  const int rA1 = wave * 16 + (lane >> 2);
  const int rA2 = rA1 + 64;
  const int cch = lane & 3;
  const int cg1 = (cch ^ ((rA1 >> 1) & 3)) * 8;  // elements
  const int cg2 = (cch ^ ((rA2 >> 1) & 3)) * 8;
  const unsigned short* pA1 = xbf + (size_t)sTok[rA1] * DM + cg1;
  const unsigned short* pA2 = xbf + (size_t)sTok[rA2] * DM + cg2;
  const unsigned short* wte = wt + (size_t)e * DM * DM;
  const unsigned short* pB1 = wte + (size_t)(n0 + rA1) * DM + cg1;
  const unsigned short* pB2 = wte + (size_t)(n0 + rA2) * DM + cg2;
  const int lo1 = wave * 512, lo2 = (wave + 4) * 512;  // 1KB per 16-row group

  const int q = lane >> 4, ml = lane & 15;
  const int wm = (wave >> 1) * 64, wn = (wave & 1) * 64;
  int offA[4], offB[4];
#pragma unroll
  for (int i = 0; i < 4; i++) {
    int row = wm + i * 16 + ml;
    offA[i] = row * 32 + (q ^ ((row >> 1) & 3)) * 8;
    int rowb = wn + i * 16 + ml;
    offB[i] = rowb * 32 + (q ^ ((rowb >> 1) & 3)) * 8;
  }

  f32x4 acc[4][4] = {};

  for (int k0 = 0; k0 < DM; k0 += 64) {
    // stage both 32-wide k-halves, one barrier
    gl_lds16(pA1 + k0, sA0 + lo1);
    gl_lds16(pA2 + k0, sA0 + lo2);
    gl_lds16(pB1 + k0, sB0 + lo1);
    gl_lds16(pB2 + k0, sB0 + lo2);
    gl_lds16(pA1 + k0 + 32, sA1 + lo1);
    gl_lds16(pA2 + k0 + 32, sA1 + lo2);
    gl_lds16(pB1 + k0 + 32, sB1 + lo1);
    gl_lds16(pB2 + k0 + 32, sB1 + lo2);
    __syncthreads();
    bf16x8 af0[4], bf0[4], af1[4], bf1[4];
#pragma unroll
    for (int i = 0; i < 4; i++) {
      af0[i] = *(const bf16x8*)(sA0 + offA[i]);
      bf0[i] = *(const bf16x8*)(sB0 + offB[i]);
      af1[i] = *(const bf16x8*)(sA1 + offA[i]);
      bf1[i] = *(const bf16x8*)(sB1 + offB[i]);
    }
#pragma unroll
    for (int mt = 0; mt < 4; mt++)
#pragma unroll
      for (int nt = 0; nt < 4; nt++)
        acc[mt][nt] = __builtin_amdgcn_mfma_f32_16x16x32_bf16(
            af0[mt], bf0[nt], acc[mt][nt], 0, 0, 0);
#pragma unroll
    for (int mt = 0; mt < 4; mt++)
#pragma unroll
      for (int nt = 0; nt < 4; nt++)
        acc[mt][nt] = __builtin_amdgcn_mfma_f32_16x16x32_bf16(
            af1[mt], bf1[nt], acc[mt][nt], 0, 0, 0);
    __syncthreads();
  }

  // epilogue: plain bf16 stores of raw accumulators (slot-major)
  const int yb = offset[e] + m0;
#pragma unroll
  for (int mt = 0; mt < 4; mt++) {
    int rbase = wm + mt * 16 + q * 4;
#pragma unroll
    for (int r = 0; r < 4; r++) {
      int row = rbase + r;
      if (m0 + row >= cnt) continue;
      unsigned short* yrow = ybuf + (size_t)(yb + row) * DM + n0;
#pragma unroll
      for (int nt = 0; nt < 4; nt++) {
        yrow[wn + nt * 16 + ml] = f2bf(acc[mt][nt][r]);
      }
    }
  }
}

// ---------------- Combine: out[t] = g0*(y0+b[e0]) + g1*(y1+b[e1]) -----------
// 4 tokens per block; float4/ushort4 fully coalesced.
__global__ __launch_bounds__(256) void combine_kernel(
    const unsigned short* __restrict__ ybuf, const int4* __restrict__ topk,
    const int2* __restrict__ pos, const int* __restrict__ offset,
    const float* __restrict__ bias, float* __restrict__ out) {
  const int c = threadIdx.x * 4;
  const int t0 = blockIdx.x * 4;
#pragma unroll
  for (int i = 0; i < 4; i++) {
    const int t = t0 + i;
    int4 r = topk[t];
    int2 p = pos[t];
    float g0 = __int_as_float(r.z), g1 = __int_as_float(r.w);
    int s0 = offset[r.x] + p.x;
    int s1 = offset[r.y] + p.y;
    ushort4 ya = *(const ushort4*)(ybuf + (size_t)s0 * DM + c);
    ushort4 yb = *(const ushort4*)(ybuf + (size_t)s1 * DM + c);
    float4 b0 = *(const float4*)(bias + (size_t)r.x * DM + c);
    float4 b1 = *(const float4*)(bias + (size_t)r.y * DM + c);
    float4 o;
    o.x = g0 * (bf2f(ya.x) + b0.x) + g1 * (bf2f(yb.x) + b1.x);
    o.y = g0 * (bf2f(ya.y) + b0.y) + g1 * (bf2f(yb.y) + b1.y);
    o.z = g0 * (bf2f(ya.z) + b0.z) + g1 * (bf2f(yb.z) + b1.z);
    o.w = g0 * (bf2f(ya.w) + b0.w) + g1 * (bf2f(yb.w) + b1.w);
    *(float4*)(out + (size_t)t * DM + c) = o;
  }
}

extern "C" void kernel_launch(void* const* d_in, const int* in_sizes, int n_in,
                              void* d_out, int out_size, void* d_ws, size_t ws_size,
                              hipStream_t stream) {
  const float* x  = (const float*)d_in[0];
  const float* Wr = (const float*)d_in[1];
  const float* br = (const float*)d_in[2];
  const float* W  = (const float*)d_in[3];
  const float* b  = (const float*)d_in[4];
  float* out = (float*)d_out;

  // workspace layout (~65.5 MB)
  char* ws = (char*)d_ws;
  unsigned short* xbf  = (unsigned short*)ws;                       // 16 MB
  unsigned short* wt   = (unsigned short*)(ws + (16u << 20));       // 16 MB
  unsigned short* ybuf = (unsigned short*)(ws + (32u << 20));       // 32 MB
  char* ctrl = ws + (64u << 20);
  int*   counts = (int*)ctrl;                                       // 32 B
  int*   ntiles = (int*)(ctrl + 64);                                // 4 B
  int*   done   = (int*)(ctrl + 96);                                // 4 B
  int*   offset = (int*)(ctrl + 128);                               // 32 B
  int*   desc   = (int*)(ctrl + 256);                               // 544 B
  int*   tok    = (int*)(ctrl + 4096);                              // 256 KB
  int2*  pos    = (int2*)(ctrl + 4096 + (256u << 10));              // 64 KB
  int4*  topk   = (int4*)(ctrl + 4096 + (320u << 10));              // 128 KB

  hipMemsetAsync(ctrl, 0, 128, stream);  // counts + ntiles + done

  prep_kernel<<<TRB + RTB, 256, 0, stream>>>(
      W, wt, x, Wr, br, xbf, topk, counts, tok, pos, done, desc, ntiles, offset);
  moe_gemm_kernel<<<dim3(8, MAXT), 256, 0, stream>>>(
      xbf, wt, counts, offset, tok, desc, ntiles, ybuf);
  combine_kernel<<<NTOK / 4, 256, 0, stream>>>(ybuf, topk, pos, offset, b, out);
}

// Round 2
// 210.341 us; speedup vs baseline: 1.0197x; 1.0060x over previous
//
#include <hip/hip_runtime.h>
#include <hip/hip_bf16.h>

// MoE: N=8192 tokens, D=1024, E=8 experts, top-2 routing.
// Inputs (fp32): x[8192,1024], Wr[1024,8], br[8], W[8,1024,1024], b[8,1024]
// Output (fp32): out[8192,1024]
//
// R1: block-aggregated scatter. R2: dense tile list. R3: split-K regressed.
// R4: atomic-free epilogue (slot-major bf16 ybuf + combine), eff. BK=64.
// R5: pipeline fusion 6 -> 3 kernels. Router branch 128 blk x 16 serial
//     tokens/wave => 61.8us latency tail (occupancy 6.4%).
// R6: router parallelism restored: 512 router blocks, 4 tokens/wave hand-
//     batched (independent chains interleaved), router blocks dispatched
//     FIRST so their tail overlaps the BW-bound transpose blocks.
//     GEMM untouched (control).

#define NTOK 8192
#define DM   1024
#define NEXP 8
#define CAP  8192    // per-expert slot capacity (worst case)
#define MAXT 136     // max total m-tiles

#define RTB  512     // router blocks (16 tokens each), dispatched first
#define TRB  2048    // transpose blocks

typedef __attribute__((ext_vector_type(8))) short bf16x8;
typedef __attribute__((ext_vector_type(4))) float f32x4;

__device__ __forceinline__ unsigned short f2bf(float f) {
  unsigned u = __float_as_uint(f);
  unsigned r = (u + 0x7fffu + ((u >> 16) & 1u)) >> 16;
  return (unsigned short)r;
}
__device__ __forceinline__ float bf2f(unsigned short s) {
  return __uint_as_float(((unsigned)s) << 16);
}

__device__ __forceinline__ void gl_lds16(const void* g, void* l) {
  __builtin_amdgcn_global_load_lds(
      (const __attribute__((address_space(1))) unsigned int*)g,
      (__attribute__((address_space(3))) unsigned int*)l, 16, 0, 0);
}

// ---------------- Fused prep: router+scatter+tilebuild | W transpose+cast ---
// Blocks [0, RTB): 16 tokens each — router logits, top-2 gates, bf16 cast of
//   x, block-aggregated slot scatter (8 global atomics/block). Each wave
//   handles 4 tokens BATCHED (independent dep chains interleaved).
//   Last router block (device done-counter) builds tile descs + offsets.
// Blocks [RTB, RTB+TRB): Wt[e][h][d] = bf16(W[e][d][h]) (64x64 LDS transpose)
__global__ __launch_bounds__(256) void prep_kernel(
    const float* __restrict__ W, unsigned short* __restrict__ Wt,
    const float* __restrict__ x, const float* __restrict__ Wr,
    const float* __restrict__ br, unsigned short* __restrict__ xbf,
    int4* __restrict__ topk, int* __restrict__ counts,
    int* __restrict__ tok, int2* __restrict__ pos,
    int* __restrict__ done, int* __restrict__ desc,
    int* __restrict__ ntiles, int* __restrict__ offset) {
  __shared__ __align__(16) float smem[64 * 65];
  const int tid = threadIdx.x;

  if (blockIdx.x >= RTB) {
    // ---- transpose branch ----
    float (*tile)[65] = (float(*)[65])smem;
    const int tb_idx = blockIdx.x - RTB;
    const int e = tb_idx >> 8;
    const int rem = tb_idx & 255;
    const int d0 = (rem >> 4) * 64, h0 = (rem & 15) * 64;
    const float* Ws = W + (size_t)e * DM * DM;
    unsigned short* Wd = Wt + (size_t)e * DM * DM;
    const int r = tid >> 4;           // 0..15
    const int c4 = (tid & 15) * 4;    // 0..60
#pragma unroll
    for (int k = 0; k < 4; k++) {
      int row = r + k * 16;
      float4 v = *(const float4*)(Ws + (size_t)(d0 + row) * DM + h0 + c4);
      tile[row][c4 + 0] = v.x; tile[row][c4 + 1] = v.y;
      tile[row][c4 + 2] = v.z; tile[row][c4 + 3] = v.w;
    }
    __syncthreads();
#pragma unroll
    for (int k = 0; k < 4; k++) {
      int hrow = r + k * 16;
      ushort4 o;
      o.x = f2bf(tile[c4 + 0][hrow]);
      o.y = f2bf(tile[c4 + 1][hrow]);
      o.z = f2bf(tile[c4 + 2][hrow]);
      o.w = f2bf(tile[c4 + 3][hrow]);
      *(ushort4*)(Wd + (size_t)(h0 + hrow) * DM + d0 + c4) = o;
    }
    return;
  }

  // ---- router + scatter branch (blocks [0, RTB)) ----
  int*  lcnt  = (int*)smem;                  // 8 ints  (counts, then bases)
  int4* ltop  = (int4*)(smem + 8);           // 16 int4 (e0,e1,g0,g1)
  int2* lrank = (int2*)(smem + 8 + 64);      // 16 int2 (block-local ranks)

  const int rb = blockIdx.x;
  const int wave = tid >> 6, lane = tid & 63;
  const int tb = rb * 16 + wave * 4;   // this wave's 4 tokens
  if (tid < NEXP) lcnt[tid] = 0;

  const int c0 = lane * 16;
  const float* wr = Wr + (size_t)c0 * NEXP;
  const float* xr = x + (size_t)tb * DM + c0;

  // batch-load 4 token rows (independent loads, latency overlapped)
  float v[4][16];
#pragma unroll
  for (int tt = 0; tt < 4; tt++) {
#pragma unroll
    for (int i = 0; i < 4; i++) {
      float4 f = *(const float4*)(xr + (size_t)tt * DM + i * 4);
      v[tt][i * 4 + 0] = f.x; v[tt][i * 4 + 1] = f.y;
      v[tt][i * 4 + 2] = f.z; v[tt][i * 4 + 3] = f.w;
    }
  }
  // bf16 cast + store
#pragma unroll
  for (int tt = 0; tt < 4; tt++) {
    union { unsigned short s[8]; uint4 q; } pk;
#pragma unroll
    for (int half = 0; half < 2; half++) {
#pragma unroll
      for (int i = 0; i < 8; i++) pk.s[i] = f2bf(v[tt][half * 8 + i]);
      *(uint4*)(xbf + (size_t)(tb + tt) * DM + c0 + half * 8) = pk.q;
    }
  }
  // 4 tokens' logit partials, interleaved
  float p[4][8] = {};
#pragma unroll
  for (int i = 0; i < 16; i++) {
    float4 wl = *(const float4*)(wr + i * 8);
    float4 wh = *(const float4*)(wr + i * 8 + 4);
#pragma unroll
    for (int tt = 0; tt < 4; tt++) {
      float xv = v[tt][i];
      p[tt][0] += xv * wl.x; p[tt][1] += xv * wl.y;
      p[tt][2] += xv * wl.z; p[tt][3] += xv * wl.w;
      p[tt][4] += xv * wh.x; p[tt][5] += xv * wh.y;
      p[tt][6] += xv * wh.z; p[tt][7] += xv * wh.w;
    }
  }
  // 4 interleaved butterfly reduces (32 independent values per stage)
#pragma unroll
  for (int off = 32; off >= 1; off >>= 1) {
#pragma unroll
    for (int tt = 0; tt < 4; tt++)
#pragma unroll
      for (int e = 0; e < 8; e++)
        p[tt][e] += __shfl_xor(p[tt][e], off, 64);
  }
  if (lane == 0) {
#pragma unroll
    for (int tt = 0; tt < 4; tt++) {
      float lg[8];
#pragma unroll
      for (int e = 0; e < 8; e++) lg[e] = p[tt][e] + br[e];
      float v0 = lg[0]; int i0 = 0;
#pragma unroll
      for (int e = 1; e < 8; e++) if (lg[e] > v0) { v0 = lg[e]; i0 = e; }
      float v1 = -3.4e38f; int i1 = 0;
#pragma unroll
      for (int e = 0; e < 8; e++)
        if (e != i0 && lg[e] > v1) { v1 = lg[e]; i1 = e; }
      float ee = __expf(v1 - v0);
      float g0 = 1.0f / (1.0f + ee);
      float g1 = ee / (1.0f + ee);
      int4 rec;
      rec.x = i0; rec.y = i1;
      rec.z = __float_as_int(g0); rec.w = __float_as_int(g1);
      ltop[wave * 4 + tt] = rec;
      topk[tb + tt] = rec;
    }
  }
  __syncthreads();

  // block-local slot ranks (16 tokens)
  if (tid < 16) {
    int4 r = ltop[tid];
    int s0 = atomicAdd(&lcnt[r.x], 1);
    int s1 = atomicAdd(&lcnt[r.y], 1);
    int2 rk; rk.x = s0; rk.y = s1;
    lrank[tid] = rk;
  }
  __syncthreads();
  // global bases (8 atomics/block); lcnt becomes base
  if (tid < NEXP) lcnt[tid] = atomicAdd(&counts[tid], lcnt[tid]);
  __syncthreads();
  if (tid < 16) {
    int4 r = ltop[tid];
    int2 rk = lrank[tid];
    int p0 = lcnt[r.x] + rk.x;
    int p1 = lcnt[r.y] + rk.y;
    int t = rb * 16 + tid;
    tok[r.x * CAP + p0] = t;
    tok[r.y * CAP + p1] = t;
    int2 pr; pr.x = p0; pr.y = p1;
    pos[t] = pr;
  }
  __syncthreads();

  // last router block builds tile descriptors + expert offsets
  if (tid == 0) {
    __threadfence();
    if (atomicAdd(done, 1) == RTB - 1) {
      __threadfence();
      int cnt[NEXP];
#pragma unroll
      for (int e = 0; e < NEXP; e++) cnt[e] = atomicAdd(&counts[e], 0);
      int idx = 0, off = 0;
#pragma unroll
      for (int e = 0; e < NEXP; e++) {
        offset[e] = off;
        off += cnt[e];
        int nm = (cnt[e] + 127) >> 7;
        for (int i = 0; i < nm; i++) desc[idx++] = (e << 16) | i;
      }
      *ntiles = idx;
    }
  }
}

// ---------------- Routed expert GEMM -> slot-major bf16 ybuf ----------------
// Tile 128x128, two BK=32 stages per barrier (eff. BK=64), 4 waves 2x2.
// Epilogue: plain bf16 stores of raw acc (gates/bias applied in combine).
__global__ __launch_bounds__(256) void moe_gemm_kernel(
    const unsigned short* __restrict__ xbf, const unsigned short* __restrict__ wt,
    const int* __restrict__ counts, const int* __restrict__ offset,
    const int* __restrict__ tok, const int* __restrict__ desc,
    const int* __restrict__ ntiles, unsigned short* __restrict__ ybuf) {
  const int slot = blockIdx.y;
  if (slot >= *ntiles) return;
  const int dsc = desc[slot];
  const int e = dsc >> 16;
  const int m0 = (dsc & 0xffff) * 128;
  const int cnt = counts[e];
  const int n0 = blockIdx.x * 128;

  __shared__ __align__(16) unsigned short sA0[128 * 32];
  __shared__ __align__(16) unsigned short sB0[128 * 32];
  __shared__ __align__(16) unsigned short sA1[128 * 32];
  __shared__ __align__(16) unsigned short sB1[128 * 32];
  __shared__ int sTok[128];

  const int tid = threadIdx.x, wave = tid >> 6, lane = tid & 63;

  if (tid < 128) {
    int sr = m0 + tid;
    int cl = (sr < cnt) ? sr : (cnt - 1);
    sTok[tid] = tok[e * CAP + cl];
  }
  __syncthreads();

  // staging: wave w stages 16-row groups {w, w+4}; lane i -> row g*16+(i>>2),
  // chunk slot i&3; source chunk XOR-swizzled (2-way LDS aliasing = free).
  const int rA1 = wave * 16 + (lane >> 2);
  const int rA2 = rA1 + 64;
  const int cch = lane & 3;
  const int cg1 = (cch ^ ((rA1 >> 1) & 3)) * 8;  // elements
  const int cg2 = (cch ^ ((rA2 >> 1) & 3)) * 8;
  const unsigned short* pA1 = xbf + (size_t)sTok[rA1] * DM + cg1;
  const unsigned short* pA2 = xbf + (size_t)sTok[rA2] * DM + cg2;
  const unsigned short* wte = wt + (size_t)e * DM * DM;
  const unsigned short* pB1 = wte + (size_t)(n0 + rA1) * DM + cg1;
  const unsigned short* pB2 = wte + (size_t)(n0 + rA2) * DM + cg2;
  const int lo1 = wave * 512, lo2 = (wave + 4) * 512;  // 1KB per 16-row group

  const int q = lane >> 4, ml = lane & 15;
  const int wm = (wave >> 1) * 64, wn = (wave & 1) * 64;
  int offA[4], offB[4];
#pragma unroll
  for (int i = 0; i < 4; i++) {
    int row = wm + i * 16 + ml;
    offA[i] = row * 32 + (q ^ ((row >> 1) & 3)) * 8;
    int rowb = wn + i * 16 + ml;
    offB[i] = rowb * 32 + (q ^ ((rowb >> 1) & 3)) * 8;
  }

  f32x4 acc[4][4] = {};

  for (int k0 = 0; k0 < DM; k0 += 64) {
    // stage both 32-wide k-halves, one barrier
    gl_lds16(pA1 + k0, sA0 + lo1);
    gl_lds16(pA2 + k0, sA0 + lo2);
    gl_lds16(pB1 + k0, sB0 + lo1);
    gl_lds16(pB2 + k0, sB0 + lo2);
    gl_lds16(pA1 + k0 + 32, sA1 + lo1);
    gl_lds16(pA2 + k0 + 32, sA1 + lo2);
    gl_lds16(pB1 + k0 + 32, sB1 + lo1);
    gl_lds16(pB2 + k0 + 32, sB1 + lo2);
    __syncthreads();
    bf16x8 af0[4], bf0[4], af1[4], bf1[4];
#pragma unroll
    for (int i = 0; i < 4; i++) {
      af0[i] = *(const bf16x8*)(sA0 + offA[i]);
      bf0[i] = *(const bf16x8*)(sB0 + offB[i]);
      af1[i] = *(const bf16x8*)(sA1 + offA[i]);
      bf1[i] = *(const bf16x8*)(sB1 + offB[i]);
    }
#pragma unroll
    for (int mt = 0; mt < 4; mt++)
#pragma unroll
      for (int nt = 0; nt < 4; nt++)
        acc[mt][nt] = __builtin_amdgcn_mfma_f32_16x16x32_bf16(
            af0[mt], bf0[nt], acc[mt][nt], 0, 0, 0);
#pragma unroll
    for (int mt = 0; mt < 4; mt++)
#pragma unroll
      for (int nt = 0; nt < 4; nt++)
        acc[mt][nt] = __builtin_amdgcn_mfma_f32_16x16x32_bf16(
            af1[mt], bf1[nt], acc[mt][nt], 0, 0, 0);
    __syncthreads();
  }

  // epilogue: plain bf16 stores of raw accumulators (slot-major)
  const int yb = offset[e] + m0;
#pragma unroll
  for (int mt = 0; mt < 4; mt++) {
    int rbase = wm + mt * 16 + q * 4;
#pragma unroll
    for (int r = 0; r < 4; r++) {
      int row = rbase + r;
      if (m0 + row >= cnt) continue;
      unsigned short* yrow = ybuf + (size_t)(yb + row) * DM + n0;
#pragma unroll
      for (int nt = 0; nt < 4; nt++) {
        yrow[wn + nt * 16 + ml] = f2bf(acc[mt][nt][r]);
      }
    }
  }
}

// ---------------- Combine: out[t] = g0*(y0+b[e0]) + g1*(y1+b[e1]) -----------
// 4 tokens per block; float4/ushort4 fully coalesced.
__global__ __launch_bounds__(256) void combine_kernel(
    const unsigned short* __restrict__ ybuf, const int4* __restrict__ topk,
    const int2* __restrict__ pos, const int* __restrict__ offset,
    const float* __restrict__ bias, float* __restrict__ out) {
  const int c = threadIdx.x * 4;
  const int t0 = blockIdx.x * 4;
#pragma unroll
  for (int i = 0; i < 4; i++) {
    const int t = t0 + i;
    int4 r = topk[t];
    int2 p = pos[t];
    float g0 = __int_as_float(r.z), g1 = __int_as_float(r.w);
    int s0 = offset[r.x] + p.x;
    int s1 = offset[r.y] + p.y;
    ushort4 ya = *(const ushort4*)(ybuf + (size_t)s0 * DM + c);
    ushort4 yb = *(const ushort4*)(ybuf + (size_t)s1 * DM + c);
    float4 b0 = *(const float4*)(bias + (size_t)r.x * DM + c);
    float4 b1 = *(const float4*)(bias + (size_t)r.y * DM + c);
    float4 o;
    o.x = g0 * (bf2f(ya.x) + b0.x) + g1 * (bf2f(yb.x) + b1.x);
    o.y = g0 * (bf2f(ya.y) + b0.y) + g1 * (bf2f(yb.y) + b1.y);
    o.z = g0 * (bf2f(ya.z) + b0.z) + g1 * (bf2f(yb.z) + b1.z);
    o.w = g0 * (bf2f(ya.w) + b0.w) + g1 * (bf2f(yb.w) + b1.w);
    *(float4*)(out + (size_t)t * DM + c) = o;
  }
}

extern "C" void kernel_launch(void* const* d_in, const int* in_sizes, int n_in,
                              void* d_out, int out_size, void* d_ws, size_t ws_size,
                              hipStream_t stream) {
  const float* x  = (const float*)d_in[0];
  const float* Wr = (const float*)d_in[1];
  const float* br = (const float*)d_in[2];
  const float* W  = (const float*)d_in[3];
  const float* b  = (const float*)d_in[4];
  float* out = (float*)d_out;

  // workspace layout (~65.5 MB)
  char* ws = (char*)d_ws;
  unsigned short* xbf  = (unsigned short*)ws;                       // 16 MB
  unsigned short* wt   = (unsigned short*)(ws + (16u << 20));       // 16 MB
  unsigned short* ybuf = (unsigned short*)(ws + (32u << 20));       // 32 MB
  char* ctrl = ws + (64u << 20);
  int*   counts = (int*)ctrl;                                       // 32 B
  int*   ntiles = (int*)(ctrl + 64);                                // 4 B
  int*   done   = (int*)(ctrl + 96);                                // 4 B
  int*   offset = (int*)(ctrl + 128);                               // 32 B
  int*   desc   = (int*)(ctrl + 256);                               // 544 B
  int*   tok    = (int*)(ctrl + 4096);                              // 256 KB
  int2*  pos    = (int2*)(ctrl + 4096 + (256u << 10));              // 64 KB
  int4*  topk   = (int4*)(ctrl + 4096 + (320u << 10));              // 128 KB

  hipMemsetAsync(ctrl, 0, 128, stream);  // counts + ntiles + done

  prep_kernel<<<RTB + TRB, 256, 0, stream>>>(
      W, wt, x, Wr, br, xbf, topk, counts, tok, pos, done, desc, ntiles, offset);
  moe_gemm_kernel<<<dim3(8, MAXT), 256, 0, stream>>>(
      xbf, wt, counts, offset, tok, desc, ntiles, ybuf);
  combine_kernel<<<NTOK / 4, 256, 0, stream>>>(ybuf, topk, pos, offset, b, out);
}

// Round 5
// 206.201 us; speedup vs baseline: 1.0402x; 1.0201x over previous
//
#include <hip/hip_runtime.h>
#include <hip/hip_bf16.h>

// MoE: N=8192 tokens, D=1024, E=8 experts, top-2 routing.
// Inputs (fp32): x[8192,1024], Wr[1024,8], br[8], W[8,1024,1024], b[8,1024]
// Output (fp32): out[8192,1024]
//
// R1: block-aggregated scatter. R2: dense tile list. R3: split-K regressed.
// R4: atomic-free epilogue (slot-major bf16 ybuf + combine), eff. BK=64.
// R5: pipeline fusion 6 -> 3 kernels. R6: router parallelism (null — the
//     60us was the W-TRANSPOSE: 64x64 tiles -> 256B/128B segments ~0.9TB/s).
// R7/R8: tr_b16 B-path — absmax FAIL (tr-read packing model wrong). REVERTED.
// R9: proven GEMM restored (Wt + swizzled ds_read_b128). Transpose rebuilt:
//     256d x 128h tile, 512B contiguous global segments BOTH sides, bf16 in
//     64KB LDS, granule swizzle pg=(dc>>2)^(h>>2) (phase1 b32 writes 4-way,
//     phase2 b128 reads ~free). Fused into prep as 256 blocks after the 512
//     router blocks; all 768 co-resident (64KB LDS -> 2 blk/CU).

#define NTOK 8192
#define DM   1024
#define NEXP 8
#define CAP  8192    // per-expert slot capacity (worst case)
#define MAXT 136     // max total m-tiles

#define RTB  512     // router blocks (16 tokens each), dispatched first
#define TRB2 256     // transpose blocks (256d x 128h tiles): 8e * 4d * 8h

typedef __attribute__((ext_vector_type(8))) short bf16x8;
typedef __attribute__((ext_vector_type(4))) float f32x4;

__device__ __forceinline__ unsigned short f2bf(float f) {
  unsigned u = __float_as_uint(f);
  unsigned r = (u + 0x7fffu + ((u >> 16) & 1u)) >> 16;
  return (unsigned short)r;
}
__device__ __forceinline__ float bf2f(unsigned short s) {
  return __uint_as_float(((unsigned)s) << 16);
}

__device__ __forceinline__ void gl_lds16(const void* g, void* l) {
  __builtin_amdgcn_global_load_lds(
      (const __attribute__((address_space(1))) unsigned int*)g,
      (__attribute__((address_space(3))) unsigned int*)l, 16, 0, 0);
}

// ---------------- Fused prep: router+scatter+tilebuild | W transpose+cast ---
// Blocks [0, RTB): 16 tokens each — router logits, top-2 gates, bf16 cast of
//   x, block-aggregated slot scatter. Last block builds tile descs/offsets.
// Blocks [RTB, RTB+TRB2): Wt[e][h][d] = bf16(W[e][d][h]) via 256d x 128h
//   tile: phase1 reads 512B row segments (float4 x2 rows, pack bf16 pairs,
//   swizzled b32 LDS writes), phase2 b128 LDS reads -> 512B global rows.
__global__ __launch_bounds__(256) void prep_kernel(
    const float* __restrict__ W, unsigned short* __restrict__ Wt,
    const float* __restrict__ x, const float* __restrict__ Wr,
    const float* __restrict__ br, unsigned short* __restrict__ xbf,
    int4* __restrict__ topk, int* __restrict__ counts,
    int* __restrict__ tok, int2* __restrict__ pos,
    int* __restrict__ done, int* __restrict__ desc,
    int* __restrict__ ntiles, int* __restrict__ offset) {
  __shared__ __align__(16) unsigned int smem4[16384];  // 64KB, both branches
  const int tid = threadIdx.x;

  if (blockIdx.x >= RTB) {
    // ---- transpose branch: tile 256d x 128h ----
    const int tb = blockIdx.x - RTB;
    const int e = tb >> 5;
    const int rem = tb & 31;
    const int D0 = (rem >> 3) * 256;   // 4 d-tiles
    const int H0 = (rem & 7) * 128;    // 8 h-tiles
    const int dp = tid >> 5;           // 0..7
    const int c  = tid & 31;           // 0..31

    // phase 1: global read (512B segments) -> packed bf16 pair -> LDS
    const float* Wsrc = W + (size_t)e * DM * DM + (size_t)D0 * DM + H0 + c * 4;
#pragma unroll 4
    for (int i = 0; i < 16; i++) {
      const int dc = dp + 8 * i;            // dword col 0..127 (d = 2dc,2dc+1)
      const int d = dc * 2;
      float4 a = *(const float4*)(Wsrc + (size_t)d * DM);
      float4 b = *(const float4*)(Wsrc + (size_t)(d + 1) * DM);
      unsigned pk[4];
      pk[0] = (unsigned)f2bf(a.x) | ((unsigned)f2bf(b.x) << 16);
      pk[1] = (unsigned)f2bf(a.y) | ((unsigned)f2bf(b.y) << 16);
      pk[2] = (unsigned)f2bf(a.z) | ((unsigned)f2bf(b.z) << 16);
      pk[3] = (unsigned)f2bf(a.w) | ((unsigned)f2bf(b.w) << 16);
#pragma unroll
      for (int j = 0; j < 4; j++) {
        const int h = c * 4 + j;                    // 0..127
        const int pg = (dc >> 2) ^ (h >> 2);        // swizzled granule 0..31
        smem4[h * 128 + pg * 4 + (dc & 3)] = pk[j];
      }
    }
    __syncthreads();

    // phase 2: b128 LDS reads (unswizzle) -> 512B contiguous global rows
    const int hp = tid >> 5;   // 0..7
    const int ch = tid & 31;   // logical granule = d-chunk of 8
    unsigned short* Wdst =
        Wt + (size_t)e * DM * DM + (size_t)H0 * DM + D0;
#pragma unroll 4
    for (int o = 0; o < 16; o++) {
      const int h = hp + 8 * o;                    // 0..127
      const int pg = ch ^ (h >> 2);                // physical granule
      uint4 v = *(const uint4*)(smem4 + h * 128 + pg * 4);
      *(uint4*)(Wdst + (size_t)h * DM + ch * 8) = v;
    }
    return;
  }

  // ---- router + scatter branch (blocks [0, RTB)) ----
  int*  lcnt  = (int*)smem4;                  // 8 ints (counts, then bases)
  int4* ltop  = (int4*)(smem4 + 8);           // 16 int4 (e0,e1,g0,g1)
  int2* lrank = (int2*)(smem4 + 72);          // 16 int2 (block-local ranks)

  const int rb = blockIdx.x;
  const int wave = tid >> 6, lane = tid & 63;
  const int tb = rb * 16 + wave * 4;   // this wave's 4 tokens
  if (tid < NEXP) lcnt[tid] = 0;

  const int c0 = lane * 16;
  const float* wr = Wr + (size_t)c0 * NEXP;
  const float* xr = x + (size_t)tb * DM + c0;

  float v[4][16];
#pragma unroll
  for (int tt = 0; tt < 4; tt++) {
#pragma unroll
    for (int i = 0; i < 4; i++) {
      float4 f = *(const float4*)(xr + (size_t)tt * DM + i * 4);
      v[tt][i * 4 + 0] = f.x; v[tt][i * 4 + 1] = f.y;
      v[tt][i * 4 + 2] = f.z; v[tt][i * 4 + 3] = f.w;
    }
  }
#pragma unroll
  for (int tt = 0; tt < 4; tt++) {
    union { unsigned short s[8]; uint4 q; } pk;
#pragma unroll
    for (int half = 0; half < 2; half++) {
#pragma unroll
      for (int i = 0; i < 8; i++) pk.s[i] = f2bf(v[tt][half * 8 + i]);
      *(uint4*)(xbf + (size_t)(tb + tt) * DM + c0 + half * 8) = pk.q;
    }
  }
  float p[4][8] = {};
#pragma unroll
  for (int i = 0; i < 16; i++) {
    float4 wl = *(const float4*)(wr + i * 8);
    float4 wh = *(const float4*)(wr + i * 8 + 4);
#pragma unroll
    for (int tt = 0; tt < 4; tt++) {
      float xv = v[tt][i];
      p[tt][0] += xv * wl.x; p[tt][1] += xv * wl.y;
      p[tt][2] += xv * wl.z; p[tt][3] += xv * wl.w;
      p[tt][4] += xv * wh.x; p[tt][5] += xv * wh.y;
      p[tt][6] += xv * wh.z; p[tt][7] += xv * wh.w;
    }
  }
#pragma unroll
  for (int off = 32; off >= 1; off >>= 1) {
#pragma unroll
    for (int tt = 0; tt < 4; tt++)
#pragma unroll
      for (int e = 0; e < 8; e++)
        p[tt][e] += __shfl_xor(p[tt][e], off, 64);
  }
  if (lane == 0) {
#pragma unroll
    for (int tt = 0; tt < 4; tt++) {
      float lg[8];
#pragma unroll
      for (int e = 0; e < 8; e++) lg[e] = p[tt][e] + br[e];
      float v0 = lg[0]; int i0 = 0;
#pragma unroll
      for (int e = 1; e < 8; e++) if (lg[e] > v0) { v0 = lg[e]; i0 = e; }
      float v1 = -3.4e38f; int i1 = 0;
#pragma unroll
      for (int e = 0; e < 8; e++)
        if (e != i0 && lg[e] > v1) { v1 = lg[e]; i1 = e; }
      float ee = __expf(v1 - v0);
      float g0 = 1.0f / (1.0f + ee);
      float g1 = ee / (1.0f + ee);
      int4 rec;
      rec.x = i0; rec.y = i1;
      rec.z = __float_as_int(g0); rec.w = __float_as_int(g1);
      ltop[wave * 4 + tt] = rec;
      topk[tb + tt] = rec;
    }
  }
  __syncthreads();

  if (tid < 16) {
    int4 r = ltop[tid];
    int s0 = atomicAdd(&lcnt[r.x], 1);
    int s1 = atomicAdd(&lcnt[r.y], 1);
    int2 rk; rk.x = s0; rk.y = s1;
    lrank[tid] = rk;
  }
  __syncthreads();
  if (tid < NEXP) lcnt[tid] = atomicAdd(&counts[tid], lcnt[tid]);
  __syncthreads();
  if (tid < 16) {
    int4 r = ltop[tid];
    int2 rk = lrank[tid];
    int p0 = lcnt[r.x] + rk.x;
    int p1 = lcnt[r.y] + rk.y;
    int t = rb * 16 + tid;
    tok[r.x * CAP + p0] = t;
    tok[r.y * CAP + p1] = t;
    int2 pr; pr.x = p0; pr.y = p1;
    pos[t] = pr;
  }
  __syncthreads();

  if (tid == 0) {
    __threadfence();
    if (atomicAdd(done, 1) == RTB - 1) {
      __threadfence();
      int cnt[NEXP];
#pragma unroll
      for (int e = 0; e < NEXP; e++) cnt[e] = atomicAdd(&counts[e], 0);
      int idx = 0, off = 0;
#pragma unroll
      for (int e = 0; e < NEXP; e++) {
        offset[e] = off;
        off += cnt[e];
        int nm = (cnt[e] + 127) >> 7;
        for (int i = 0; i < nm; i++) desc[idx++] = (e << 16) | i;
      }
      *ntiles = idx;
    }
  }
}

// ---------------- Routed expert GEMM -> slot-major bf16 ybuf ----------------
// (PROVEN R4/R6 form.) Tile 128x128, two BK=32 stages per barrier (eff.
// BK=64), 4 waves 2x2. Epilogue: plain bf16 stores of raw accumulators.
__global__ __launch_bounds__(256) void moe_gemm_kernel(
    const unsigned short* __restrict__ xbf, const unsigned short* __restrict__ wt,
    const int* __restrict__ counts, const int* __restrict__ offset,
    const int* __restrict__ tok, const int* __restrict__ desc,
    const int* __restrict__ ntiles, unsigned short* __restrict__ ybuf) {
  const int slot = blockIdx.y;
  if (slot >= *ntiles) return;
  const int dsc = desc[slot];
  const int e = dsc >> 16;
  const int m0 = (dsc & 0xffff) * 128;
  const int cnt = counts[e];
  const int n0 = blockIdx.x * 128;

  __shared__ __align__(16) unsigned short sA0[128 * 32];
  __shared__ __align__(16) unsigned short sB0[128 * 32];
  __shared__ __align__(16) unsigned short sA1[128 * 32];
  __shared__ __align__(16) unsigned short sB1[128 * 32];
  __shared__ int sTok[128];

  const int tid = threadIdx.x, wave = tid >> 6, lane = tid & 63;

  if (tid < 128) {
    int sr = m0 + tid;
    int cl = (sr < cnt) ? sr : (cnt - 1);
    sTok[tid] = tok[e * CAP + cl];
  }
  __syncthreads();

  // staging: wave w stages 16-row groups {w, w+4}; lane i -> row g*16+(i>>2),
  // chunk slot i&3; source chunk XOR-swizzled (2-way LDS aliasing = free).
  const int rA1 = wave * 16 + (lane >> 2);
  const int rA2 = rA1 + 64;
  const int cch = lane & 3;
  const int cg1 = (cch ^ ((rA1 >> 1) & 3)) * 8;  // elements
  const int cg2 = (cch ^ ((rA2 >> 1) & 3)) * 8;
  const unsigned short* pA1 = xbf + (size_t)sTok[rA1] * DM + cg1;
  const unsigned short* pA2 = xbf + (size_t)sTok[rA2] * DM + cg2;
  const unsigned short* wte = wt + (size_t)e * DM * DM;
  const unsigned short* pB1 = wte + (size_t)(n0 + rA1) * DM + cg1;
  const unsigned short* pB2 = wte + (size_t)(n0 + rA2) * DM + cg2;
  const int lo1 = wave * 512, lo2 = (wave + 4) * 512;  // 1KB per 16-row group

  const int q = lane >> 4, ml = lane & 15;
  const int wm = (wave >> 1) * 64, wn = (wave & 1) * 64;
  int offA[4], offB[4];
#pragma unroll
  for (int i = 0; i < 4; i++) {
    int row = wm + i * 16 + ml;
    offA[i] = row * 32 + (q ^ ((row >> 1) & 3)) * 8;
    int rowb = wn + i * 16 + ml;
    offB[i] = rowb * 32 + (q ^ ((rowb >> 1) & 3)) * 8;
  }

  f32x4 acc[4][4] = {};

  for (int k0 = 0; k0 < DM; k0 += 64) {
    // stage both 32-wide k-halves, one barrier
    gl_lds16(pA1 + k0, sA0 + lo1);
    gl_lds16(pA2 + k0, sA0 + lo2);
    gl_lds16(pB1 + k0, sB0 + lo1);
    gl_lds16(pB2 + k0, sB0 + lo2);
    gl_lds16(pA1 + k0 + 32, sA1 + lo1);
    gl_lds16(pA2 + k0 + 32, sA1 + lo2);
    gl_lds16(pB1 + k0 + 32, sB1 + lo1);
    gl_lds16(pB2 + k0 + 32, sB1 + lo2);
    __syncthreads();
    bf16x8 af0[4], bf0[4], af1[4], bf1[4];
#pragma unroll
    for (int i = 0; i < 4; i++) {
      af0[i] = *(const bf16x8*)(sA0 + offA[i]);
      bf0[i] = *(const bf16x8*)(sB0 + offB[i]);
      af1[i] = *(const bf16x8*)(sA1 + offA[i]);
      bf1[i] = *(const bf16x8*)(sB1 + offB[i]);
    }
#pragma unroll
    for (int mt = 0; mt < 4; mt++)
#pragma unroll
      for (int nt = 0; nt < 4; nt++)
        acc[mt][nt] = __builtin_amdgcn_mfma_f32_16x16x32_bf16(
            af0[mt], bf0[nt], acc[mt][nt], 0, 0, 0);
#pragma unroll
    for (int mt = 0; mt < 4; mt++)
#pragma unroll
      for (int nt = 0; nt < 4; nt++)
        acc[mt][nt] = __builtin_amdgcn_mfma_f32_16x16x32_bf16(
            af1[mt], bf1[nt], acc[mt][nt], 0, 0, 0);
    __syncthreads();
  }

  // epilogue: plain bf16 stores of raw accumulators (slot-major)
  const int yb = offset[e] + m0;
#pragma unroll
  for (int mt = 0; mt < 4; mt++) {
    int rbase = wm + mt * 16 + q * 4;
#pragma unroll
    for (int r = 0; r < 4; r++) {
      int row = rbase + r;
      if (m0 + row >= cnt) continue;
      unsigned short* yrow = ybuf + (size_t)(yb + row) * DM + n0;
#pragma unroll
      for (int nt = 0; nt < 4; nt++) {
        yrow[wn + nt * 16 + ml] = f2bf(acc[mt][nt][r]);
      }
    }
  }
}

// ---------------- Combine: out[t] = g0*(y0+b[e0]) + g1*(y1+b[e1]) -----------
__global__ __launch_bounds__(256) void combine_kernel(
    const unsigned short* __restrict__ ybuf, const int4* __restrict__ topk,
    const int2* __restrict__ pos, const int* __restrict__ offset,
    const float* __restrict__ bias, float* __restrict__ out) {
  const int c = threadIdx.x * 4;
  const int t0 = blockIdx.x * 4;
#pragma unroll
  for (int i = 0; i < 4; i++) {
    const int t = t0 + i;
    int4 r = topk[t];
    int2 p = pos[t];
    float g0 = __int_as_float(r.z), g1 = __int_as_float(r.w);
    int s0 = offset[r.x] + p.x;
    int s1 = offset[r.y] + p.y;
    ushort4 ya = *(const ushort4*)(ybuf + (size_t)s0 * DM + c);
    ushort4 yb = *(const ushort4*)(ybuf + (size_t)s1 * DM + c);
    float4 b0 = *(const float4*)(bias + (size_t)r.x * DM + c);
    float4 b1 = *(const float4*)(bias + (size_t)r.y * DM + c);
    float4 o;
    o.x = g0 * (bf2f(ya.x) + b0.x) + g1 * (bf2f(yb.x) + b1.x);
    o.y = g0 * (bf2f(ya.y) + b0.y) + g1 * (bf2f(yb.y) + b1.y);
    o.z = g0 * (bf2f(ya.z) + b0.z) + g1 * (bf2f(yb.z) + b1.z);
    o.w = g0 * (bf2f(ya.w) + b0.w) + g1 * (bf2f(yb.w) + b1.w);
    *(float4*)(out + (size_t)t * DM + c) = o;
  }
}

extern "C" void kernel_launch(void* const* d_in, const int* in_sizes, int n_in,
                              void* d_out, int out_size, void* d_ws, size_t ws_size,
                              hipStream_t stream) {
  const float* x  = (const float*)d_in[0];
  const float* Wr = (const float*)d_in[1];
  const float* br = (const float*)d_in[2];
  const float* W  = (const float*)d_in[3];
  const float* b  = (const float*)d_in[4];
  float* out = (float*)d_out;

  // workspace layout (~65.5 MB)
  char* ws = (char*)d_ws;
  unsigned short* xbf  = (unsigned short*)ws;                       // 16 MB
  unsigned short* wt   = (unsigned short*)(ws + (16u << 20));       // 16 MB
  unsigned short* ybuf = (unsigned short*)(ws + (32u << 20));       // 32 MB
  char* ctrl = ws + (64u << 20);
  int*   counts = (int*)ctrl;                                       // 32 B
  int*   ntiles = (int*)(ctrl + 64);                                // 4 B
  int*   done   = (int*)(ctrl + 96);                                // 4 B
  int*   offset = (int*)(ctrl + 128);                               // 32 B
  int*   desc   = (int*)(ctrl + 256);                               // 544 B
  int*   tok    = (int*)(ctrl + 4096);                              // 256 KB
  int2*  pos    = (int2*)(ctrl + 4096 + (256u << 10));              // 64 KB
  int4*  topk   = (int4*)(ctrl + 4096 + (320u << 10));              // 128 KB

  hipMemsetAsync(ctrl, 0, 128, stream);  // counts + ntiles + done

  prep_kernel<<<RTB + TRB2, 256, 0, stream>>>(
      W, wt, x, Wr, br, xbf, topk, counts, tok, pos, done, desc, ntiles, offset);
  moe_gemm_kernel<<<dim3(8, MAXT), 256, 0, stream>>>(
      xbf, wt, counts, offset, tok, desc, ntiles, ybuf);
  combine_kernel<<<NTOK / 4, 256, 0, stream>>>(ybuf, topk, pos, offset, b, out);
}